// Round 1
// baseline (97.406 us; speedup 1.0000x reference)
//
#include <hip/hip_runtime.h>

#define FXc 384.996f
#define FYc 384.996f
#define CXc 325.85f
#define CYc 237.646f
#define DEPTH_MARGIN 0.003f
#define IMG_H 480
#define IMG_W 640

// ---------- tiny kernel: T = inv(pose_B) @ pose_A ----------
__global__ void compute_T_kernel(const float* __restrict__ poseA,
                                 const float* __restrict__ poseB,
                                 float* __restrict__ T) {
    if (threadIdx.x != 0 || blockIdx.x != 0) return;
    float m[16], inv[16];
#pragma unroll
    for (int i = 0; i < 16; ++i) m[i] = poseB[i];

    // Adjugate-based 4x4 inverse (layout-agnostic: inv(M^T) = inv(M)^T).
    inv[0]  =  m[5]*m[10]*m[15] - m[5]*m[11]*m[14] - m[9]*m[6]*m[15] + m[9]*m[7]*m[14] + m[13]*m[6]*m[11] - m[13]*m[7]*m[10];
    inv[4]  = -m[4]*m[10]*m[15] + m[4]*m[11]*m[14] + m[8]*m[6]*m[15] - m[8]*m[7]*m[14] - m[12]*m[6]*m[11] + m[12]*m[7]*m[10];
    inv[8]  =  m[4]*m[9]*m[15]  - m[4]*m[11]*m[13] - m[8]*m[5]*m[15] + m[8]*m[7]*m[13] + m[12]*m[5]*m[11] - m[12]*m[7]*m[9];
    inv[12] = -m[4]*m[9]*m[14]  + m[4]*m[10]*m[13] + m[8]*m[5]*m[14] - m[8]*m[6]*m[13] - m[12]*m[5]*m[10] + m[12]*m[6]*m[9];
    inv[1]  = -m[1]*m[10]*m[15] + m[1]*m[11]*m[14] + m[9]*m[2]*m[15] - m[9]*m[3]*m[14] - m[13]*m[2]*m[11] + m[13]*m[3]*m[10];
    inv[5]  =  m[0]*m[10]*m[15] - m[0]*m[11]*m[14] - m[8]*m[2]*m[15] + m[8]*m[3]*m[14] + m[12]*m[2]*m[11] - m[12]*m[3]*m[10];
    inv[9]  = -m[0]*m[9]*m[15]  + m[0]*m[11]*m[13] + m[8]*m[1]*m[15] - m[8]*m[3]*m[13] - m[12]*m[1]*m[11] + m[12]*m[3]*m[9];
    inv[13] =  m[0]*m[9]*m[14]  - m[0]*m[10]*m[13] - m[8]*m[1]*m[14] + m[8]*m[2]*m[13] + m[12]*m[1]*m[10] - m[12]*m[2]*m[9];
    inv[2]  =  m[1]*m[6]*m[15]  - m[1]*m[7]*m[14]  - m[5]*m[2]*m[15] + m[5]*m[3]*m[14] + m[13]*m[2]*m[7]  - m[13]*m[3]*m[6];
    inv[6]  = -m[0]*m[6]*m[15]  + m[0]*m[7]*m[14]  + m[4]*m[2]*m[15] - m[4]*m[3]*m[14] - m[12]*m[2]*m[7]  + m[12]*m[3]*m[6];
    inv[10] =  m[0]*m[5]*m[15]  - m[0]*m[7]*m[13]  - m[4]*m[1]*m[15] + m[4]*m[3]*m[13] + m[12]*m[1]*m[7]  - m[12]*m[3]*m[5];
    inv[14] = -m[0]*m[5]*m[14]  + m[0]*m[6]*m[13]  + m[4]*m[1]*m[14] - m[4]*m[2]*m[13] - m[12]*m[1]*m[6]  + m[12]*m[2]*m[5];
    inv[3]  = -m[1]*m[6]*m[11]  + m[1]*m[7]*m[10]  + m[5]*m[2]*m[11] - m[5]*m[3]*m[10] - m[9]*m[2]*m[7]   + m[9]*m[3]*m[6];
    inv[7]  =  m[0]*m[6]*m[11]  - m[0]*m[7]*m[10]  - m[4]*m[2]*m[11] + m[4]*m[3]*m[10] + m[8]*m[2]*m[7]   - m[8]*m[3]*m[6];
    inv[11] = -m[0]*m[5]*m[11]  + m[0]*m[7]*m[9]   + m[4]*m[1]*m[11] - m[4]*m[3]*m[9]  - m[8]*m[1]*m[7]   + m[8]*m[3]*m[5];
    inv[15] =  m[0]*m[5]*m[10]  - m[0]*m[6]*m[9]   - m[4]*m[1]*m[10] + m[4]*m[2]*m[9]  + m[8]*m[1]*m[6]   - m[8]*m[2]*m[5];

    float det = m[0]*inv[0] + m[1]*inv[4] + m[2]*inv[8] + m[3]*inv[12];
    float rdet = 1.0f / det;
#pragma unroll
    for (int i = 0; i < 16; ++i) inv[i] *= rdet;

    // T = inv(poseB) @ poseA  (row-major)
#pragma unroll
    for (int r = 0; r < 4; ++r)
#pragma unroll
        for (int c = 0; c < 4; ++c) {
            float acc = 0.f;
#pragma unroll
            for (int k = 0; k < 4; ++k) acc += inv[r*4 + k] * poseA[k*4 + c];
            T[r*4 + c] = acc;
        }
}

// ---------- main kernel: 4 samples / thread ----------
__global__ __launch_bounds__(256) void corr_kernel(
    const float* __restrict__ depthA, const float* __restrict__ depthB,
    const int*   __restrict__ uA,     const int*   __restrict__ vA,
    const float* __restrict__ T,      float* __restrict__ out,
    int n4, int n) {
    const float t00 = T[0],  t01 = T[1],  t02 = T[2],  t03 = T[3];
    const float t10 = T[4],  t11 = T[5],  t12 = T[6],  t13 = T[7];
    const float t20 = T[8],  t21 = T[9],  t22 = T[10], t23 = T[11];

    const int stride = gridDim.x * blockDim.x;
    for (int i = blockIdx.x * blockDim.x + threadIdx.x; i < n4; i += stride) {
        int4 u4 = ((const int4*)uA)[i];
        int4 v4 = ((const int4*)vA)[i];
        float4 o[3];
        float* op = (float*)o;
        const int us[4] = {u4.x, u4.y, u4.z, u4.w};
        const int vs[4] = {v4.x, v4.y, v4.z, v4.w};
#pragma unroll
        for (int j = 0; j < 4; ++j) {
            const int u = us[j], v = vs[j];
            const int pix = v * IMG_W + u;
            const float z  = depthA[pix];
            const float dB = depthB[pix];
            const float x = ((float)u - CXc) * z / FXc;
            const float y = ((float)v - CYc) * z / FYc;
            const float pbx = t00*x + t01*y + t02*z + t03;
            const float pby = t10*x + t11*y + t12*z + t13;
            const float pbz = t20*x + t21*y + t22*z + t23;
            const float uB = FXc * pbx / pbz + CXc;
            const float vB = FYc * pby / pbz + CYc;
            const float uBi = truncf(uB);
            const float vBi = truncf(vB);
            const bool valid = (z > 0.f)
                & (uBi > 0.f) & (uBi < (float)IMG_W)
                & (vBi > 0.f) & (vBi < (float)IMG_H)
                & (dB > 0.f) & (dB >= pbz - DEPTH_MARGIN);
            op[j*3 + 0] = uB;
            op[j*3 + 1] = vB;
            op[j*3 + 2] = valid ? 1.f : 0.f;
        }
        float4* ob = (float4*)out + (size_t)i * 3;
        ob[0] = o[0];
        ob[1] = o[1];
        ob[2] = o[2];
    }
    // tail (N not divisible by 4) — handled by first threads of block 0
    const int tail0 = n4 * 4;
    const int gtid = blockIdx.x * blockDim.x + threadIdx.x;
    for (int s = tail0 + gtid; s < n; s += stride) {
        const int u = uA[s], v = vA[s];
        const int pix = v * IMG_W + u;
        const float z  = depthA[pix];
        const float dB = depthB[pix];
        const float x = ((float)u - CXc) * z / FXc;
        const float y = ((float)v - CYc) * z / FYc;
        const float pbx = t00*x + t01*y + t02*z + t03;
        const float pby = t10*x + t11*y + t12*z + t13;
        const float pbz = t20*x + t21*y + t22*z + t23;
        const float uB = FXc * pbx / pbz + CXc;
        const float vB = FYc * pby / pbz + CYc;
        const float uBi = truncf(uB);
        const float vBi = truncf(vB);
        const bool valid = (z > 0.f)
            & (uBi > 0.f) & (uBi < (float)IMG_W)
            & (vBi > 0.f) & (vBi < (float)IMG_H)
            & (dB > 0.f) & (dB >= pbz - DEPTH_MARGIN);
        out[(size_t)s*3 + 0] = uB;
        out[(size_t)s*3 + 1] = vB;
        out[(size_t)s*3 + 2] = valid ? 1.f : 0.f;
    }
}

extern "C" void kernel_launch(void* const* d_in, const int* in_sizes, int n_in,
                              void* d_out, int out_size, void* d_ws, size_t ws_size,
                              hipStream_t stream) {
    // setup_inputs order:
    // 0: in_A (unused)  1: depth_A  2: pose_A  3: in_B (unused)
    // 4: depth_B        5: pose_B   6: u_A     7: v_A
    const float* depthA = (const float*)d_in[1];
    const float* poseA  = (const float*)d_in[2];
    const float* depthB = (const float*)d_in[4];
    const float* poseB  = (const float*)d_in[5];
    const int*   uA     = (const int*)d_in[6];
    const int*   vA     = (const int*)d_in[7];
    float* out = (float*)d_out;
    float* T   = (float*)d_ws;

    const int n  = in_sizes[6];
    const int n4 = n / 4;

    compute_T_kernel<<<1, 64, 0, stream>>>(poseA, poseB, T);

    int blocks = (n4 + 255) / 256;
    if (blocks > 2048) blocks = 2048;
    if (blocks < 1) blocks = 1;
    corr_kernel<<<blocks, 256, 0, stream>>>(depthA, depthB, uA, vA, T, out, n4, n);
}